// Round 9
// baseline (43.324 us; speedup 1.0000x reference)
//
#include <hip/hip_runtime.h>
#include <hip/hip_fp16.h>

#define H 64
#define W 64
#define NPIX 4096          // 64*64
#define GHH 240
#define GWW 240
#define CB 512             // total channels in data
#define CX 256             // x channels
#define NT4  16            // taps packed 4-per-uint4

// ---------- helpers ----------
// pack: byte-offset (idx*16, <=65520) in HIGH 16, f16 weight in LOW 16.
static __device__ __forceinline__ unsigned pk_wi(float w, unsigned idx) {
    const unsigned short hw = __half_as_ushort(__float2half(w));
    return ((idx * 16u) << 16) | (unsigned)hw;
}
// pack two f32 -> packed f16 pair (v_cvt_pkrtz_f16_f32, one instruction)
static __device__ __forceinline__ unsigned pk_f16(float a, float b) {
    __half2 h = __floats2half2_rn(a, b);
    return *reinterpret_cast<unsigned*>(&h);
}

// ---------- kernel 1: per (b,pixel) 64-tap packed stencil -> ws ----------
// grid: 256 blocks x 128 threads (all CUs); b = blockIdx&7 -> XCD pinning so
// batch-b stencil lands in the L2 of the XCD that gathers batch b.
__global__ __launch_bounds__(128)
void stencil_kernel(const float* __restrict__ data, uint4* __restrict__ st) {
    const int b   = blockIdx.x & 7;
    const int pix = (blockIdx.x >> 3) * 128 + threadIdx.x;
    const int oy = pix >> 6, ox = pix & 63;

    const float*  xbase = data + (size_t)b * CB * NPIX;
    const float2* gaff  = (const float2*)(xbase + (size_t)256 * NPIX);
    const float2* gtps  = (const float2*)(xbase + (size_t)384 * NPIX);
    uint4* stb = st + (size_t)b * NT4 * NPIX;

    const float fy  = ((float)oy / 63.0f) * 239.0f;
    const float fx  = ((float)ox / 63.0f) * 239.0f;
    const float fy0 = floorf(fy), fx0 = floorf(fx);
    const float wy1 = fy - fy0,  wx1 = fx - fx0;

#pragma unroll
    for (int t = 0; t < 4; ++t) {
        const int tty = t >> 1, ttx = t & 1;
        const float gyf = fy0 + (float)tty;
        const float gxf = fx0 + (float)ttx;
        float wt = (tty ? wy1 : 1.0f - wy1) * (ttx ? wx1 : 1.0f - wx1);
        if (gyf < 0.0f || gyf > 239.0f || gxf < 0.0f || gxf > 239.0f) wt = 0.0f;
        const int gyi = min(max((int)gyf, 0), GHH - 1);
        const int gxi = min(max((int)gxf, 0), GWW - 1);

        const float2 gt = gtps[gyi * GWW + gxi];
        const float sx  = (gt.x + 1.0f) * 0.5f * 239.0f;
        const float sy  = (gt.y + 1.0f) * 0.5f * 239.0f;
        const float sy0 = floorf(sy), sx0 = floorf(sx);
        const float wsy1 = sy - sy0,  wsx1 = sx - sx0;

#pragma unroll
        for (int s = 0; s < 4; ++s) {
            const int ssy = s >> 1, ssx = s & 1;
            const float ayf = sy0 + (float)ssy;
            const float axf = sx0 + (float)ssx;
            float ws = (ssy ? wsy1 : 1.0f - wsy1) * (ssx ? wsx1 : 1.0f - wsx1);
            if (ayf < 0.0f || ayf > 239.0f || axf < 0.0f || axf > 239.0f) ws = 0.0f;
            ws *= wt;
            const int ayi = min(max((int)ayf, 0), GHH - 1);
            const int axi = min(max((int)axf, 0), GWW - 1);

            const float2 ga = gaff[ayi * GWW + axi];
            const float qx  = (ga.x + 1.0f) * 0.5f * 63.0f;
            const float qy  = (ga.y + 1.0f) * 0.5f * 63.0f;
            const float qy0 = floorf(qy), qx0 = floorf(qx);
            const float wqy1 = qy - qy0,  wqx1 = qx - qx0;

            unsigned pk[4];
#pragma unroll
            for (int r = 0; r < 4; ++r) {
                const int rry = r >> 1, rrx = r & 1;
                const float byf = qy0 + (float)rry;
                const float bxf = qx0 + (float)rrx;
                float wr = (rry ? wqy1 : 1.0f - wqy1) * (rrx ? wqx1 : 1.0f - wqx1);
                if (byf < 0.0f || byf > 63.0f || bxf < 0.0f || bxf > 63.0f) wr = 0.0f;
                wr *= ws;
                const int byi = min(max((int)byf, 0), H - 1);
                const int bxi = min(max((int)bxf, 0), W - 1);
                pk[r] = pk_wi(wr, (unsigned)(byi * W + bxi));
            }
            stb[(size_t)(t * 4 + s) * NPIX + pix] = make_uint4(pk[0], pk[1], pk[2], pk[3]);
        }
    }
}

// ---------- kernel 2: gather over f16-packed LDS, fma_mix accumulate ----------
// grid: 8 b x 32 cg x 2 halves = 512 blocks x 1024 threads; 64 KB LDS each
// -> 2 blocks/CU, 32 waves/CU. Two interleaved pixel chains (pg0/pg1),
// residual + lead stencil loads hoisted above the barrier.
__global__ __launch_bounds__(1024, 8)
void gather_kernel(const float* __restrict__ data, const uint4* __restrict__ st,
                   float* __restrict__ out) {
    __shared__ uint4 xl[NPIX];   // 64 KB: pixel -> 8 channels packed f16
    const int tid  = threadIdx.x;
    const int b    = blockIdx.x & 7;        // XCD pinning heuristic
    const int cg   = (blockIdx.x >> 3) & 31;
    const int half = blockIdx.x >> 8;       // 0/1: pixel half
    const int c0   = cg * 8;

    const float* xbase = data + (size_t)b * CB * NPIX;
    const float* xc    = xbase + (size_t)c0 * NPIX;

    // stage full 8-channel image: 8 x float4 coalesced loads, register transpose,
    // pack to f16 via v_cvt_pkrtz (1 instr / 2 channels)
    {
        float4 va[8];
#pragma unroll
        for (int c = 0; c < 8; ++c)
            va[c] = ((const float4*)(xc + (size_t)c * NPIX))[tid];
#pragma unroll
        for (int k = 0; k < 4; ++k) {
            uint4 u;
            u.x = pk_f16(((const float*)&va[0])[k], ((const float*)&va[1])[k]);
            u.y = pk_f16(((const float*)&va[2])[k], ((const float*)&va[3])[k]);
            u.z = pk_f16(((const float*)&va[4])[k], ((const float*)&va[5])[k]);
            u.w = pk_f16(((const float*)&va[6])[k], ((const float*)&va[7])[k]);
            xl[tid * 4 + k] = u;
        }
    }

    const uint4* stb = st + (size_t)b * NT4 * NPIX;
    const char*  xlb = (const char*)xl;
    const int pixA = half * 2048 + tid;          // chain A
    const int pixB = pixA + 1024;                // chain B

    // hoisted (pre-barrier) residual + lead stencil loads: their L2 latency
    // hides under the staging drain / barrier wait
    float resA[8], resB[8];
#pragma unroll
    for (int c = 0; c < 8; ++c) {
        resA[c] = xc[(size_t)c * NPIX + pixA];
        resB[c] = xc[(size_t)c * NPIX + pixB];
    }
    uint4 aC = stb[pixA];
    uint4 bC = stb[pixB];
    uint4 aN = stb[(size_t)1 * NPIX + pixA];
    uint4 bN = stb[(size_t)1 * NPIX + pixB];

    __syncthreads();

    float a0 = 0.f, a1 = 0.f, a2 = 0.f, a3 = 0.f;
    float a4 = 0.f, a5 = 0.f, a6 = 0.f, a7 = 0.f;
    float b0 = 0.f, b1 = 0.f, b2 = 0.f, b3 = 0.f;
    float b4 = 0.f, b5 = 0.f, b6 = 0.f, b7 = 0.f;

#pragma unroll
    for (int g = 0; g < NT4; ++g) {
        const uint4 sa = aC; aC = aN;
        const uint4 sb = bC; bC = bN;
        if (g + 2 < NT4) {
            aN = stb[(size_t)(g + 2) * NPIX + pixA];
            bN = stb[(size_t)(g + 2) * NPIX + pixB];
        }
#pragma unroll
        for (int r = 0; r < 4; ++r) {
            const unsigned ua = (&sa.x)[r];
            const unsigned ub = (&sb.x)[r];
            const float wa = __half2float(__ushort_as_half((unsigned short)(ua & 0xffffu)));
            const float wb = __half2float(__ushort_as_half((unsigned short)(ub & 0xffffu)));
            const uint4 va = *(const uint4*)(xlb + (ua >> 16));
            const uint4 vb = *(const uint4*)(xlb + (ub >> 16));
            const __half2 ha01 = *reinterpret_cast<const __half2*>(&va.x);
            const __half2 ha23 = *reinterpret_cast<const __half2*>(&va.y);
            const __half2 ha45 = *reinterpret_cast<const __half2*>(&va.z);
            const __half2 ha67 = *reinterpret_cast<const __half2*>(&va.w);
            const __half2 hb01 = *reinterpret_cast<const __half2*>(&vb.x);
            const __half2 hb23 = *reinterpret_cast<const __half2*>(&vb.y);
            const __half2 hb45 = *reinterpret_cast<const __half2*>(&vb.z);
            const __half2 hb67 = *reinterpret_cast<const __half2*>(&vb.w);
            a0 = fmaf(wa, __half2float(__low2half (ha01)), a0);
            a1 = fmaf(wa, __half2float(__high2half(ha01)), a1);
            a2 = fmaf(wa, __half2float(__low2half (ha23)), a2);
            a3 = fmaf(wa, __half2float(__high2half(ha23)), a3);
            a4 = fmaf(wa, __half2float(__low2half (ha45)), a4);
            a5 = fmaf(wa, __half2float(__high2half(ha45)), a5);
            a6 = fmaf(wa, __half2float(__low2half (ha67)), a6);
            a7 = fmaf(wa, __half2float(__high2half(ha67)), a7);
            b0 = fmaf(wb, __half2float(__low2half (hb01)), b0);
            b1 = fmaf(wb, __half2float(__high2half(hb01)), b1);
            b2 = fmaf(wb, __half2float(__low2half (hb23)), b2);
            b3 = fmaf(wb, __half2float(__high2half(hb23)), b3);
            b4 = fmaf(wb, __half2float(__low2half (hb45)), b4);
            b5 = fmaf(wb, __half2float(__high2half(hb45)), b5);
            b6 = fmaf(wb, __half2float(__low2half (hb67)), b6);
            b7 = fmaf(wb, __half2float(__high2half(hb67)), b7);
        }
    }

    // residual add + coalesced plain stores (full lines through L2)
    float* oA = out + ((size_t)b * CX + c0) * NPIX + pixA;
    float* oB = out + ((size_t)b * CX + c0) * NPIX + pixB;
    oA[0 * NPIX] = resA[0] + a0;  oB[0 * NPIX] = resB[0] + b0;
    oA[1 * NPIX] = resA[1] + a1;  oB[1 * NPIX] = resB[1] + b1;
    oA[2 * NPIX] = resA[2] + a2;  oB[2 * NPIX] = resB[2] + b2;
    oA[3 * NPIX] = resA[3] + a3;  oB[3 * NPIX] = resB[3] + b3;
    oA[4 * NPIX] = resA[4] + a4;  oB[4 * NPIX] = resB[4] + b4;
    oA[5 * NPIX] = resA[5] + a5;  oB[5 * NPIX] = resB[5] + b5;
    oA[6 * NPIX] = resA[6] + a6;  oB[6 * NPIX] = resB[6] + b6;
    oA[7 * NPIX] = resA[7] + a7;  oB[7 * NPIX] = resB[7] + b7;
}

// ---------- fallback (round-2 proven kernel) if ws too small ----------
__global__ __launch_bounds__(1024, 4)
void warp_resblock_mono(const float* __restrict__ data, float* __restrict__ out) {
    const int tid = threadIdx.x;
    const int b   = blockIdx.x & 7;
    const int cg  = blockIdx.x >> 3;
    const int c0  = cg * 8;

    const float*  xbase = data + (size_t)b * CB * NPIX;
    const float2* gaff  = (const float2*)(xbase + (size_t)256 * NPIX);
    const float2* gtps  = (const float2*)(xbase + (size_t)384 * NPIX);

    __shared__ float4 xa[NPIX];
    __shared__ float4 xb[NPIX];
    {
        const float4* xs = (const float4*)(xbase + (size_t)c0 * NPIX);
        float4 va[4], vb[4];
#pragma unroll
        for (int cc = 0; cc < 4; ++cc) va[cc] = xs[(size_t)cc * 1024 + tid];
#pragma unroll
        for (int cc = 0; cc < 4; ++cc) vb[cc] = xs[(size_t)(4 + cc) * 1024 + tid];
#pragma unroll
        for (int k = 0; k < 4; ++k) {
            const int pix = tid * 4 + k;
            xa[pix] = make_float4(((const float*)&va[0])[k], ((const float*)&va[1])[k],
                                  ((const float*)&va[2])[k], ((const float*)&va[3])[k]);
            xb[pix] = make_float4(((const float*)&vb[0])[k], ((const float*)&vb[1])[k],
                                  ((const float*)&vb[2])[k], ((const float*)&vb[3])[k]);
        }
    }
    __syncthreads();

    for (int pg = 0; pg < 4; ++pg) {
        const int pix = pg * 1024 + tid;
        const int oy = pix >> 6, ox = pix & 63;
        float a0 = 0.f, a1 = 0.f, a2 = 0.f, a3 = 0.f;
        float a4 = 0.f, a5 = 0.f, a6 = 0.f, a7 = 0.f;

        const float fy  = ((float)oy / 63.0f) * 239.0f;
        const float fx  = ((float)ox / 63.0f) * 239.0f;
        const float fy0 = floorf(fy), fx0 = floorf(fx);
        const float wy1 = fy - fy0,  wx1 = fx - fx0;

#pragma unroll
        for (int t = 0; t < 4; ++t) {
            const int tty = t >> 1, ttx = t & 1;
            const float gyf = fy0 + (float)tty;
            const float gxf = fx0 + (float)ttx;
            float wt = (tty ? wy1 : 1.0f - wy1) * (ttx ? wx1 : 1.0f - wx1);
            if (gyf < 0.0f || gyf > 239.0f || gxf < 0.0f || gxf > 239.0f) wt = 0.0f;
            const int gyi = min(max((int)gyf, 0), GHH - 1);
            const int gxi = min(max((int)gxf, 0), GWW - 1);
            const float2 gt = gtps[gyi * GWW + gxi];
            const float sx  = (gt.x + 1.0f) * 0.5f * 239.0f;
            const float sy  = (gt.y + 1.0f) * 0.5f * 239.0f;
            const float sy0 = floorf(sy), sx0 = floorf(sx);
            const float wsy1 = sy - sy0,  wsx1 = sx - sx0;
#pragma unroll
            for (int s = 0; s < 4; ++s) {
                const int ssy = s >> 1, ssx = s & 1;
                const float ayf = sy0 + (float)ssy;
                const float axf = sx0 + (float)ssx;
                float ws = (ssy ? wsy1 : 1.0f - wsy1) * (ssx ? wsx1 : 1.0f - wsx1);
                if (ayf < 0.0f || ayf > 239.0f || axf < 0.0f || axf > 239.0f) ws = 0.0f;
                ws *= wt;
                const int ayi = min(max((int)ayf, 0), GHH - 1);
                const int axi = min(max((int)axf, 0), GWW - 1);
                const float2 ga = gaff[ayi * GWW + axi];
                const float qx  = (ga.x + 1.0f) * 0.5f * 63.0f;
                const float qy  = (ga.y + 1.0f) * 0.5f * 63.0f;
                const float qy0 = floorf(qy), qx0 = floorf(qx);
                const float wqy1 = qy - qy0,  wqx1 = qx - qx0;
#pragma unroll
                for (int r = 0; r < 4; ++r) {
                    const int rry = r >> 1, rrx = r & 1;
                    const float byf = qy0 + (float)rry;
                    const float bxf = qx0 + (float)rrx;
                    float wr = (rry ? wqy1 : 1.0f - wqy1) * (rrx ? wqx1 : 1.0f - wqx1);
                    if (byf < 0.0f || byf > 63.0f || bxf < 0.0f || bxf > 63.0f) wr = 0.0f;
                    wr *= ws;
                    const int byi = min(max((int)byf, 0), H - 1);
                    const int bxi = min(max((int)bxf, 0), W - 1);
                    const int idx = byi * W + bxi;
                    const float4 pa = xa[idx];
                    const float4 pb = xb[idx];
                    a0 = fmaf(wr, pa.x, a0); a1 = fmaf(wr, pa.y, a1);
                    a2 = fmaf(wr, pa.z, a2); a3 = fmaf(wr, pa.w, a3);
                    a4 = fmaf(wr, pb.x, a4); a5 = fmaf(wr, pb.y, a5);
                    a6 = fmaf(wr, pb.z, a6); a7 = fmaf(wr, pb.w, a7);
                }
            }
        }
        const float4 ra = xa[pix];
        const float4 rb = xb[pix];
        float* o = out + ((size_t)b * CX + c0) * NPIX + pix;
        o[0 * NPIX] = ra.x + a0; o[1 * NPIX] = ra.y + a1;
        o[2 * NPIX] = ra.z + a2; o[3 * NPIX] = ra.w + a3;
        o[4 * NPIX] = rb.x + a4; o[5 * NPIX] = rb.y + a5;
        o[6 * NPIX] = rb.z + a6; o[7 * NPIX] = rb.w + a7;
    }
}

extern "C" void kernel_launch(void* const* d_in, const int* in_sizes, int n_in,
                              void* d_out, int out_size, void* d_ws, size_t ws_size,
                              hipStream_t stream) {
    (void)in_sizes; (void)n_in; (void)out_size;
    const float* data = (const float*)d_in[0];
    float* out = (float*)d_out;
    const size_t ws_needed = (size_t)8 * NT4 * NPIX * sizeof(uint4);  // 8.39 MB

    if (ws_size >= ws_needed) {
        uint4* st = (uint4*)d_ws;
        hipLaunchKernelGGL(stencil_kernel, dim3(256), dim3(128), 0, stream, data, st);
        hipLaunchKernelGGL(gather_kernel, dim3(512), dim3(1024), 0, stream, data, st, out);
    } else {
        hipLaunchKernelGGL(warp_resblock_mono, dim3(256), dim3(1024), 0, stream, data, out);
    }
}